// Round 1
// baseline (503.886 us; speedup 1.0000x reference)
//
#include <hip/hip_runtime.h>
#include <hip/hip_bf16.h>
#include <stdint.h>

// Problem constants
#define B_N 1024
#define S_N 65536
#define D_N 512
#define SCALE 8.0f
#define KSPLIT 16
#define KCHUNK (S_N / KSPLIT)   // 4096

typedef __attribute__((ext_vector_type(8))) short bf16x8;   // 8 bf16 in 4 VGPRs (guide §3)
typedef __attribute__((ext_vector_type(4))) float f32x4;

// ---- workspace layout (bytes) ----
#define OFF_MBF   ((size_t)0)                                  // M bf16 (s,d)   64 MiB
#define OFF_MT    (OFF_MBF + (size_t)S_N * D_N * 2)            // M^T bf16 (d,s) 64 MiB
#define OFF_XBF   (OFF_MT  + (size_t)D_N * S_N * 2)            // X bf16         1 MiB
#define OFF_P     (OFF_XBF + (size_t)B_N * D_N * 2)            // P=exp bf16     128 MiB
#define OFF_XNSQ  (OFF_P   + (size_t)B_N * S_N * 2)            // ||x||^2        4 KiB
#define OFF_MNSQ  (OFF_XNSQ + (size_t)B_N * 4)                 // ||m||^2        256 KiB
#define OFF_LSUM  (OFF_MNSQ + (size_t)S_N * 4)                 // softmax denom  4 KiB
#define OFF_OPART (OFF_LSUM + (size_t)B_N * 4)                 // PV partials    32 MiB
// total ~ 289.3 MiB

__device__ __forceinline__ unsigned short f2bf(float f) {
  unsigned u = __builtin_bit_cast(unsigned, f);
  u += 0x7fffu + ((u >> 16) & 1u);          // RNE
  return (unsigned short)(u >> 16);
}

__device__ __forceinline__ void stage16(const unsigned short* g, unsigned short* l) {
  // async global->LDS, 16B/lane; LDS dest is wave-uniform base + lane*16
  __builtin_amdgcn_global_load_lds(
      (const __attribute__((address_space(1))) void*)g,
      (__attribute__((address_space(3))) void*)l, 16, 0, 0);
}

// ---------------- prep X: bf16 convert + ||x||^2 ----------------
__global__ void k_prep_x(const float* __restrict__ X, unsigned short* __restrict__ Xbf,
                         float* __restrict__ xnsq) {
  const int row = blockIdx.x;
  const int t = threadIdx.x;  // 0..127
  float4 v = ((const float4*)(X + (size_t)row * D_N))[t];
  float ss = v.x*v.x + v.y*v.y + v.z*v.z + v.w*v.w;
  ushort4 o; o.x = f2bf(v.x); o.y = f2bf(v.y); o.z = f2bf(v.z); o.w = f2bf(v.w);
  ((ushort4*)(Xbf + (size_t)row * D_N))[t] = o;
  #pragma unroll
  for (int m = 1; m < 64; m <<= 1) ss += __shfl_xor(ss, m);
  __shared__ float partial[2];
  if ((t & 63) == 0) partial[t >> 6] = ss;
  __syncthreads();
  if (t == 0) xnsq[row] = partial[0] + partial[1];
}

// ------- prep M: bf16 convert, LDS-transpose to Mt, ||m||^2 (no atomics) -------
__global__ void k_prep_m(const float* __restrict__ M, unsigned short* __restrict__ Mbf,
                         unsigned short* __restrict__ Mt, float* __restrict__ mnsq) {
  __shared__ float ts[64 * 65];             // 64x64 tile, +1 pad -> conflict-free transpose
  const int t = threadIdx.x;                // 256
  const int s0 = blockIdx.x * 64;
  const int r = t >> 2, cq = t & 3;         // load role: row r, 16-col chunk cq
  const int c = t >> 2, sq = t & 3;         // store role: Mt row c, 16-s chunk sq
  float ss = 0.f;
  for (int ct = 0; ct < 8; ++ct) {
    float f[16];
    const float4* src = (const float4*)(M + (size_t)(s0 + r) * D_N + ct * 64 + cq * 16);
    #pragma unroll
    for (int k = 0; k < 4; ++k) {
      float4 v = src[k];
      f[4*k+0] = v.x; f[4*k+1] = v.y; f[4*k+2] = v.z; f[4*k+3] = v.w;
    }
    union { unsigned short u[16]; uint4 v4[2]; } pk;
    #pragma unroll
    for (int j = 0; j < 16; ++j) {
      ss += f[j] * f[j];
      pk.u[j] = f2bf(f[j]);
      ts[r * 65 + cq * 16 + j] = f[j];
    }
    uint4* dst = (uint4*)(Mbf + (size_t)(s0 + r) * D_N + ct * 64 + cq * 16);
    dst[0] = pk.v4[0]; dst[1] = pk.v4[1];
    __syncthreads();
    union { unsigned short u[16]; uint4 v4[2]; } pt;
    #pragma unroll
    for (int j = 0; j < 16; ++j) pt.u[j] = f2bf(ts[(sq * 16 + j) * 65 + c]);
    uint4* dt = (uint4*)(Mt + (size_t)(ct * 64 + c) * S_N + s0 + sq * 16);
    dt[0] = pt.v4[0]; dt[1] = pt.v4[1];
    __syncthreads();
  }
  ss += __shfl_xor(ss, 1);
  ss += __shfl_xor(ss, 2);
  if (cq == 0) mnsq[s0 + r] = ss;
}

// ---------------- QK gemm_bt + exp epilogue + row-sum atomics ----------------
// C[b][s] = sum_d Xbf[b][d]*Mbf[s][d]; P = exp(8*C/sqrt(xnsq*mnsq)); lsum += rowsum
__global__ __launch_bounds__(256, 2) void k_qk(
    const unsigned short* __restrict__ Xbf, const unsigned short* __restrict__ Mbf,
    const float* __restrict__ xnsq, const float* __restrict__ mnsq,
    unsigned short* __restrict__ P, float* __restrict__ lsum) {
  __shared__ unsigned short As[128 * 64];
  __shared__ unsigned short Bs[128 * 64];
  const int t = threadIdx.x;
  const int w = t >> 6, lane = t & 63, quad = lane >> 4, l15 = lane & 15;
  const int wr = w >> 1, wc = w & 1;
  const int bm = blockIdx.x, bn = blockIdx.y;  // x=bm(8) fast so 8 readers of a B-tile co-resident

  f32x4 acc[4][4];
  #pragma unroll
  for (int i = 0; i < 4; ++i)
    #pragma unroll
    for (int j = 0; j < 4; ++j) acc[i][j] = (f32x4){0.f, 0.f, 0.f, 0.f};

  const int srow = t >> 3, schunk = t & 7;
  const unsigned short* gA = Xbf + (size_t)(bm * 128 + srow) * D_N + schunk * 8;
  const unsigned short* gB = Mbf + (size_t)(bn * 128 + srow) * D_N + schunk * 8;
  unsigned short* lA = As + w * 512;
  unsigned short* lB = Bs + w * 512;

  for (int k0 = 0; k0 < D_N; k0 += 64) {
    #pragma unroll
    for (int i = 0; i < 4; ++i) {
      stage16(gA + (size_t)(i * 32) * D_N + k0, lA + i * 2048);
      stage16(gB + (size_t)(i * 32) * D_N + k0, lB + i * 2048);
    }
    __syncthreads();
    #pragma unroll
    for (int kk = 0; kk < 64; kk += 32) {
      bf16x8 af[4], bfr[4];
      #pragma unroll
      for (int i = 0; i < 4; ++i)
        af[i] = *(const bf16x8*)&As[(wr * 64 + i * 16 + l15) * 64 + kk + quad * 8];
      #pragma unroll
      for (int j = 0; j < 4; ++j)
        bfr[j] = *(const bf16x8*)&Bs[(wc * 64 + j * 16 + l15) * 64 + kk + quad * 8];
      #pragma unroll
      for (int i = 0; i < 4; ++i)
        #pragma unroll
        for (int j = 0; j < 4; ++j)
          acc[i][j] = __builtin_amdgcn_mfma_f32_16x16x32_bf16(af[i], bfr[j], acc[i][j], 0, 0, 0);
    }
    __syncthreads();
  }

  float mn_[4];
  #pragma unroll
  for (int j = 0; j < 4; ++j) mn_[j] = mnsq[bn * 128 + wc * 64 + j * 16 + l15];
  #pragma unroll
  for (int i = 0; i < 4; ++i) {
    float rowsum[4];
    #pragma unroll
    for (int r = 0; r < 4; ++r) {
      const int b = bm * 128 + wr * 64 + i * 16 + quad * 4 + r;
      const float xq = xnsq[b];
      float rs = 0.f;
      #pragma unroll
      for (int j = 0; j < 4; ++j) {
        float d2 = fmaxf(xq * mn_[j], 1e-16f);      // matches max(||x||*||m||,1e-8)
        float p = __expf(SCALE * acc[i][j][r] * rsqrtf(d2));
        rs += p;
        const int s = bn * 128 + wc * 64 + j * 16 + l15;
        P[(size_t)b * S_N + s] = f2bf(p);
      }
      rowsum[r] = rs;
    }
    #pragma unroll
    for (int r = 0; r < 4; ++r) {
      float rs = rowsum[r];
      rs += __shfl_xor(rs, 1);
      rs += __shfl_xor(rs, 2);
      rs += __shfl_xor(rs, 4);
      rs += __shfl_xor(rs, 8);
      if (l15 == 0) {
        const int b = bm * 128 + wr * 64 + i * 16 + quad * 4 + r;
        unsafeAtomicAdd(&lsum[b], rs);
      }
    }
  }
}

// ---------------- PV gemm_bt (K-split) ----------------
// Opart[ks][b][d] = sum_{s in chunk} P[b][s] * Mt[d][s]
__global__ __launch_bounds__(256, 2) void k_pv(
    const unsigned short* __restrict__ P, const unsigned short* __restrict__ Mt,
    float* __restrict__ Opart) {
  __shared__ unsigned short As[128 * 64];
  __shared__ unsigned short Bs[128 * 64];
  const int t = threadIdx.x;
  const int w = t >> 6, lane = t & 63, quad = lane >> 4, l15 = lane & 15;
  const int wr = w >> 1, wc = w & 1;
  const int bn = blockIdx.x, bm = blockIdx.y, ks = blockIdx.z;

  f32x4 acc[4][4];
  #pragma unroll
  for (int i = 0; i < 4; ++i)
    #pragma unroll
    for (int j = 0; j < 4; ++j) acc[i][j] = (f32x4){0.f, 0.f, 0.f, 0.f};

  const int srow = t >> 3, schunk = t & 7;
  const unsigned short* gA = P  + (size_t)(bm * 128 + srow) * S_N + (size_t)ks * KCHUNK + schunk * 8;
  const unsigned short* gB = Mt + (size_t)(bn * 128 + srow) * S_N + (size_t)ks * KCHUNK + schunk * 8;
  unsigned short* lA = As + w * 512;
  unsigned short* lB = Bs + w * 512;

  for (int k0 = 0; k0 < KCHUNK; k0 += 64) {
    #pragma unroll
    for (int i = 0; i < 4; ++i) {
      stage16(gA + (size_t)(i * 32) * S_N + k0, lA + i * 2048);
      stage16(gB + (size_t)(i * 32) * S_N + k0, lB + i * 2048);
    }
    __syncthreads();
    #pragma unroll
    for (int kk = 0; kk < 64; kk += 32) {
      bf16x8 af[4], bfr[4];
      #pragma unroll
      for (int i = 0; i < 4; ++i)
        af[i] = *(const bf16x8*)&As[(wr * 64 + i * 16 + l15) * 64 + kk + quad * 8];
      #pragma unroll
      for (int j = 0; j < 4; ++j)
        bfr[j] = *(const bf16x8*)&Bs[(wc * 64 + j * 16 + l15) * 64 + kk + quad * 8];
      #pragma unroll
      for (int i = 0; i < 4; ++i)
        #pragma unroll
        for (int j = 0; j < 4; ++j)
          acc[i][j] = __builtin_amdgcn_mfma_f32_16x16x32_bf16(af[i], bfr[j], acc[i][j], 0, 0, 0);
    }
    __syncthreads();
  }

  float* Od = Opart + (size_t)ks * (B_N * D_N);
  #pragma unroll
  for (int i = 0; i < 4; ++i)
    #pragma unroll
    for (int r = 0; r < 4; ++r) {
      const int b = bm * 128 + wr * 64 + i * 16 + quad * 4 + r;
      #pragma unroll
      for (int j = 0; j < 4; ++j) {
        const int d = bn * 128 + wc * 64 + j * 16 + l15;
        Od[(size_t)b * D_N + d] = acc[i][j][r];
      }
    }
}

// ---------------- combine: out = (sum_ks Opart) / lsum ----------------
__global__ void k_combine(const float* __restrict__ Opart, const float* __restrict__ lsum,
                          float* __restrict__ out) {
  const int idx = blockIdx.x * 256 + threadIdx.x;  // float4 index, 131072 total
  const int b = idx >> 7;                          // (idx*4)/512
  float4 s = {0.f, 0.f, 0.f, 0.f};
  #pragma unroll
  for (int ks = 0; ks < KSPLIT; ++ks) {
    float4 v = ((const float4*)Opart)[(size_t)ks * (B_N * D_N / 4) + idx];
    s.x += v.x; s.y += v.y; s.z += v.z; s.w += v.w;
  }
  const float inv = 1.0f / lsum[b];
  s.x *= inv; s.y *= inv; s.z *= inv; s.w *= inv;
  ((float4*)out)[idx] = s;
}

extern "C" void kernel_launch(void* const* d_in, const int* in_sizes, int n_in,
                              void* d_out, int out_size, void* d_ws, size_t ws_size,
                              hipStream_t stream) {
  const float* X = (const float*)d_in[0];
  const float* M = (const float*)d_in[1];
  char* ws = (char*)d_ws;
  unsigned short* Mbf  = (unsigned short*)(ws + OFF_MBF);
  unsigned short* Mt   = (unsigned short*)(ws + OFF_MT);
  unsigned short* Xbf  = (unsigned short*)(ws + OFF_XBF);
  unsigned short* P    = (unsigned short*)(ws + OFF_P);
  float* xnsq = (float*)(ws + OFF_XNSQ);
  float* mnsq = (float*)(ws + OFF_MNSQ);
  float* lsum = (float*)(ws + OFF_LSUM);
  float* Opart = (float*)(ws + OFF_OPART);

  hipMemsetAsync(lsum, 0, B_N * sizeof(float), stream);
  k_prep_x<<<dim3(B_N), 128, 0, stream>>>(X, Xbf, xnsq);
  k_prep_m<<<dim3(S_N / 64), 256, 0, stream>>>(M, Mbf, Mt, mnsq);
  k_qk<<<dim3(8, S_N / 128), 256, 0, stream>>>(Xbf, Mbf, xnsq, mnsq, P, lsum);
  k_pv<<<dim3(D_N / 128, B_N / 128, KSPLIT), 256, 0, stream>>>(P, Mt, Opart);
  k_combine<<<dim3(B_N * D_N / 4 / 256), 256, 0, stream>>>(Opart, lsum, (float*)d_out);
}

// Round 2
// 488.403 us; speedup vs baseline: 1.0317x; 1.0317x over previous
//
#include <hip/hip_runtime.h>
#include <hip/hip_bf16.h>
#include <stdint.h>

// Problem constants
#define B_N 1024
#define S_N 65536
#define D_N 512
#define SCALE 8.0f
#define KSPLIT 16
#define KCHUNK (S_N / KSPLIT)   // 4096

typedef __attribute__((ext_vector_type(8))) short bf16x8;   // 8 bf16 in 4 VGPRs (guide §3)
typedef __attribute__((ext_vector_type(4))) float f32x4;

// ---- workspace layout (bytes) ----
#define OFF_MBF   ((size_t)0)                                  // M bf16 (s,d)   64 MiB
#define OFF_MT    (OFF_MBF + (size_t)S_N * D_N * 2)            // M^T bf16 (d,s) 64 MiB
#define OFF_XBF   (OFF_MT  + (size_t)D_N * S_N * 2)            // X bf16         1 MiB
#define OFF_P     (OFF_XBF + (size_t)B_N * D_N * 2)            // P=exp bf16     128 MiB
#define OFF_XNSQ  (OFF_P   + (size_t)B_N * S_N * 2)            // ||x||^2        4 KiB
#define OFF_MNSQ  (OFF_XNSQ + (size_t)B_N * 4)                 // ||m||^2        256 KiB
#define OFF_LSUM  (OFF_MNSQ + (size_t)S_N * 4)                 // softmax denom  4 KiB
#define OFF_OPART (OFF_LSUM + (size_t)B_N * 4)                 // PV partials    32 MiB
// total ~ 289.3 MiB

__device__ __forceinline__ unsigned short f2bf(float f) {
  unsigned u = __builtin_bit_cast(unsigned, f);
  u += 0x7fffu + ((u >> 16) & 1u);          // RNE
  return (unsigned short)(u >> 16);
}

__device__ __forceinline__ void stage16(const unsigned short* g, unsigned short* l) {
  // async global->LDS, 16B/lane; LDS dest is wave-uniform base + lane*16
  __builtin_amdgcn_global_load_lds(
      (const __attribute__((address_space(1))) void*)g,
      (__attribute__((address_space(3))) void*)l, 16, 0, 0);
}

// ---------------- prep X: bf16 convert + ||x||^2 ----------------
__global__ void k_prep_x(const float* __restrict__ X, unsigned short* __restrict__ Xbf,
                         float* __restrict__ xnsq) {
  const int row = blockIdx.x;
  const int t = threadIdx.x;  // 0..127
  float4 v = ((const float4*)(X + (size_t)row * D_N))[t];
  float ss = v.x*v.x + v.y*v.y + v.z*v.z + v.w*v.w;
  ushort4 o; o.x = f2bf(v.x); o.y = f2bf(v.y); o.z = f2bf(v.z); o.w = f2bf(v.w);
  ((ushort4*)(Xbf + (size_t)row * D_N))[t] = o;
  #pragma unroll
  for (int m = 1; m < 64; m <<= 1) ss += __shfl_xor(ss, m);
  __shared__ float partial[2];
  if ((t & 63) == 0) partial[t >> 6] = ss;
  __syncthreads();
  if (t == 0) xnsq[row] = partial[0] + partial[1];
}

// ------- prep M: bf16 convert, LDS-transpose to Mt, ||m||^2 (no atomics) -------
__global__ void k_prep_m(const float* __restrict__ M, unsigned short* __restrict__ Mbf,
                         unsigned short* __restrict__ Mt, float* __restrict__ mnsq) {
  __shared__ float ts[64 * 65];             // 64x64 tile, +1 pad -> conflict-free transpose
  const int t = threadIdx.x;                // 256
  const int s0 = blockIdx.x * 64;
  const int r = t >> 2, cq = t & 3;         // load role: row r, 16-col chunk cq
  const int c = t >> 2, sq = t & 3;         // store role: Mt row c, 16-s chunk sq
  float ss = 0.f;
  for (int ct = 0; ct < 8; ++ct) {
    float f[16];
    const float4* src = (const float4*)(M + (size_t)(s0 + r) * D_N + ct * 64 + cq * 16);
    #pragma unroll
    for (int k = 0; k < 4; ++k) {
      float4 v = src[k];
      f[4*k+0] = v.x; f[4*k+1] = v.y; f[4*k+2] = v.z; f[4*k+3] = v.w;
    }
    union { unsigned short u[16]; uint4 v4[2]; } pk;
    #pragma unroll
    for (int j = 0; j < 16; ++j) {
      ss += f[j] * f[j];
      pk.u[j] = f2bf(f[j]);
      ts[r * 65 + cq * 16 + j] = f[j];
    }
    uint4* dst = (uint4*)(Mbf + (size_t)(s0 + r) * D_N + ct * 64 + cq * 16);
    dst[0] = pk.v4[0]; dst[1] = pk.v4[1];
    __syncthreads();
    union { unsigned short u[16]; uint4 v4[2]; } pt;
    #pragma unroll
    for (int j = 0; j < 16; ++j) pt.u[j] = f2bf(ts[(sq * 16 + j) * 65 + c]);
    uint4* dt = (uint4*)(Mt + (size_t)(ct * 64 + c) * S_N + s0 + sq * 16);
    dt[0] = pt.v4[0]; dt[1] = pt.v4[1];
    __syncthreads();
  }
  ss += __shfl_xor(ss, 1);
  ss += __shfl_xor(ss, 2);
  if (cq == 0) mnsq[s0 + r] = ss;
}

// ---------------- QK gemm_bt + exp epilogue + row-sum atomics ----------------
// LDS layout is XOR-swizzled: logical 16B-chunk c of row r lives at physical
// chunk c ^ (r&7). Stager loads global chunk (c ^ (srow&7)) into phys chunk c
// (global_load_lds can't scatter, so the permutation is on the source side).
// Readers: phys = (quad + kk/8) ^ (row&7) -> all 32 banks uniform, 2-way max.
__global__ __launch_bounds__(256, 2) void k_qk(
    const unsigned short* __restrict__ Xbf, const unsigned short* __restrict__ Mbf,
    const float* __restrict__ xnsq, const float* __restrict__ mnsq,
    unsigned short* __restrict__ P, float* __restrict__ lsum) {
  __shared__ unsigned short As[128 * 64];
  __shared__ unsigned short Bs[128 * 64];
  const int t = threadIdx.x;
  const int w = t >> 6, lane = t & 63, quad = lane >> 4, l15 = lane & 15;
  const int wr = w >> 1, wc = w & 1;
  const int x7 = l15 & 7;                       // row&7 for fragment reads
  const int bm = blockIdx.x, bn = blockIdx.y;

  f32x4 acc[4][4];
  #pragma unroll
  for (int i = 0; i < 4; ++i)
    #pragma unroll
    for (int j = 0; j < 4; ++j) acc[i][j] = (f32x4){0.f, 0.f, 0.f, 0.f};

  const int srow = t >> 3;
  const int schunk = (t & 7) ^ (srow & 7);      // inverse swizzle at load time
  const unsigned short* gA = Xbf + (size_t)(bm * 128 + srow) * D_N + schunk * 8;
  const unsigned short* gB = Mbf + (size_t)(bn * 128 + srow) * D_N + schunk * 8;
  unsigned short* lA = As + w * 512;
  unsigned short* lB = Bs + w * 512;

  for (int k0 = 0; k0 < D_N; k0 += 64) {
    #pragma unroll
    for (int i = 0; i < 4; ++i) {
      stage16(gA + (size_t)(i * 32) * D_N + k0, lA + i * 2048);
      stage16(gB + (size_t)(i * 32) * D_N + k0, lB + i * 2048);
    }
    __syncthreads();
    #pragma unroll
    for (int kk = 0; kk < 64; kk += 32) {
      const int cq = (kk >> 3) + quad;          // logical chunk
      bf16x8 af[4], bfr[4];
      #pragma unroll
      for (int i = 0; i < 4; ++i)
        af[i] = *(const bf16x8*)&As[(wr * 64 + i * 16 + l15) * 64 + (cq ^ x7) * 8];
      #pragma unroll
      for (int j = 0; j < 4; ++j)
        bfr[j] = *(const bf16x8*)&Bs[(wc * 64 + j * 16 + l15) * 64 + (cq ^ x7) * 8];
      #pragma unroll
      for (int i = 0; i < 4; ++i)
        #pragma unroll
        for (int j = 0; j < 4; ++j)
          acc[i][j] = __builtin_amdgcn_mfma_f32_16x16x32_bf16(af[i], bfr[j], acc[i][j], 0, 0, 0);
    }
    __syncthreads();
  }

  float mn_[4];
  #pragma unroll
  for (int j = 0; j < 4; ++j) mn_[j] = mnsq[bn * 128 + wc * 64 + j * 16 + l15];
  #pragma unroll
  for (int i = 0; i < 4; ++i) {
    float rowsum[4];
    #pragma unroll
    for (int r = 0; r < 4; ++r) {
      const int b = bm * 128 + wr * 64 + i * 16 + quad * 4 + r;
      const float xq = xnsq[b];
      float rs = 0.f;
      #pragma unroll
      for (int j = 0; j < 4; ++j) {
        float d2 = fmaxf(xq * mn_[j], 1e-16f);      // matches max(||x||*||m||,1e-8)
        float p = __expf(SCALE * acc[i][j][r] * rsqrtf(d2));
        rs += p;
        const int s = bn * 128 + wc * 64 + j * 16 + l15;
        P[(size_t)b * S_N + s] = f2bf(p);
      }
      rowsum[r] = rs;
    }
    #pragma unroll
    for (int r = 0; r < 4; ++r) {
      float rs = rowsum[r];
      rs += __shfl_xor(rs, 1);
      rs += __shfl_xor(rs, 2);
      rs += __shfl_xor(rs, 4);
      rs += __shfl_xor(rs, 8);
      if (l15 == 0) {
        const int b = bm * 128 + wr * 64 + i * 16 + quad * 4 + r;
        unsafeAtomicAdd(&lsum[b], rs);
      }
    }
  }
}

// ---------------- PV gemm_bt (K-split), same LDS swizzle ----------------
// Opart[ks][b][d] = sum_{s in chunk} P[b][s] * Mt[d][s]
__global__ __launch_bounds__(256, 2) void k_pv(
    const unsigned short* __restrict__ P, const unsigned short* __restrict__ Mt,
    float* __restrict__ Opart) {
  __shared__ unsigned short As[128 * 64];
  __shared__ unsigned short Bs[128 * 64];
  const int t = threadIdx.x;
  const int w = t >> 6, lane = t & 63, quad = lane >> 4, l15 = lane & 15;
  const int wr = w >> 1, wc = w & 1;
  const int x7 = l15 & 7;
  const int bn = blockIdx.x, bm = blockIdx.y, ks = blockIdx.z;

  f32x4 acc[4][4];
  #pragma unroll
  for (int i = 0; i < 4; ++i)
    #pragma unroll
    for (int j = 0; j < 4; ++j) acc[i][j] = (f32x4){0.f, 0.f, 0.f, 0.f};

  const int srow = t >> 3;
  const int schunk = (t & 7) ^ (srow & 7);
  const unsigned short* gA = P  + (size_t)(bm * 128 + srow) * S_N + (size_t)ks * KCHUNK + schunk * 8;
  const unsigned short* gB = Mt + (size_t)(bn * 128 + srow) * S_N + (size_t)ks * KCHUNK + schunk * 8;
  unsigned short* lA = As + w * 512;
  unsigned short* lB = Bs + w * 512;

  for (int k0 = 0; k0 < KCHUNK; k0 += 64) {
    #pragma unroll
    for (int i = 0; i < 4; ++i) {
      stage16(gA + (size_t)(i * 32) * S_N + k0, lA + i * 2048);
      stage16(gB + (size_t)(i * 32) * S_N + k0, lB + i * 2048);
    }
    __syncthreads();
    #pragma unroll
    for (int kk = 0; kk < 64; kk += 32) {
      const int cq = (kk >> 3) + quad;
      bf16x8 af[4], bfr[4];
      #pragma unroll
      for (int i = 0; i < 4; ++i)
        af[i] = *(const bf16x8*)&As[(wr * 64 + i * 16 + l15) * 64 + (cq ^ x7) * 8];
      #pragma unroll
      for (int j = 0; j < 4; ++j)
        bfr[j] = *(const bf16x8*)&Bs[(wc * 64 + j * 16 + l15) * 64 + (cq ^ x7) * 8];
      #pragma unroll
      for (int i = 0; i < 4; ++i)
        #pragma unroll
        for (int j = 0; j < 4; ++j)
          acc[i][j] = __builtin_amdgcn_mfma_f32_16x16x32_bf16(af[i], bfr[j], acc[i][j], 0, 0, 0);
    }
    __syncthreads();
  }

  float* Od = Opart + (size_t)ks * (B_N * D_N);
  #pragma unroll
  for (int i = 0; i < 4; ++i)
    #pragma unroll
    for (int r = 0; r < 4; ++r) {
      const int b = bm * 128 + wr * 64 + i * 16 + quad * 4 + r;
      #pragma unroll
      for (int j = 0; j < 4; ++j) {
        const int d = bn * 128 + wc * 64 + j * 16 + l15;
        Od[(size_t)b * D_N + d] = acc[i][j][r];
      }
    }
}

// ---------------- combine: out = (sum_ks Opart) / lsum ----------------
__global__ void k_combine(const float* __restrict__ Opart, const float* __restrict__ lsum,
                          float* __restrict__ out) {
  const int idx = blockIdx.x * 256 + threadIdx.x;  // float4 index, 131072 total
  const int b = idx >> 7;                          // (idx*4)/512
  float4 s = {0.f, 0.f, 0.f, 0.f};
  #pragma unroll
  for (int ks = 0; ks < KSPLIT; ++ks) {
    float4 v = ((const float4*)Opart)[(size_t)ks * (B_N * D_N / 4) + idx];
    s.x += v.x; s.y += v.y; s.z += v.z; s.w += v.w;
  }
  const float inv = 1.0f / lsum[b];
  s.x *= inv; s.y *= inv; s.z *= inv; s.w *= inv;
  ((float4*)out)[idx] = s;
}

extern "C" void kernel_launch(void* const* d_in, const int* in_sizes, int n_in,
                              void* d_out, int out_size, void* d_ws, size_t ws_size,
                              hipStream_t stream) {
  const float* X = (const float*)d_in[0];
  const float* M = (const float*)d_in[1];
  char* ws = (char*)d_ws;
  unsigned short* Mbf  = (unsigned short*)(ws + OFF_MBF);
  unsigned short* Mt   = (unsigned short*)(ws + OFF_MT);
  unsigned short* Xbf  = (unsigned short*)(ws + OFF_XBF);
  unsigned short* P    = (unsigned short*)(ws + OFF_P);
  float* xnsq = (float*)(ws + OFF_XNSQ);
  float* mnsq = (float*)(ws + OFF_MNSQ);
  float* lsum = (float*)(ws + OFF_LSUM);
  float* Opart = (float*)(ws + OFF_OPART);

  hipMemsetAsync(lsum, 0, B_N * sizeof(float), stream);
  k_prep_x<<<dim3(B_N), 128, 0, stream>>>(X, Xbf, xnsq);
  k_prep_m<<<dim3(S_N / 64), 256, 0, stream>>>(M, Mbf, Mt, mnsq);
  k_qk<<<dim3(8, S_N / 128), 256, 0, stream>>>(Xbf, Mbf, xnsq, mnsq, P, lsum);
  k_pv<<<dim3(D_N / 128, B_N / 128, KSPLIT), 256, 0, stream>>>(P, Mt, Opart);
  k_combine<<<dim3(B_N * D_N / 4 / 256), 256, 0, stream>>>(Opart, lsum, (float*)d_out);
}